// Round 8
// baseline (81.499 us; speedup 1.0000x reference)
//
#include <hip/hip_runtime.h>

#define EMB 128
#define KN 16
#define NREL 32

__device__ __forceinline__ float fast_tanh(float x) {
    // exact identity tanh(x) = 1 - 2/(e^{2x}+1); v_exp-based, ~1e-6 abs err.
    const float z = __expf(2.0f * x);
    return 1.0f - __fdividef(2.0f, z + 1.0f);
}

// ---------------- costab: |cos(rela[r], rela[c])| for all 32x32 pairs -------
__global__ __launch_bounds__(256) void pgra_costab_k(const float* __restrict__ rela,
                                                     float* __restrict__ costab) {
    const int pair = blockIdx.x * 4 + (threadIdx.x >> 6);
    const int lane = threadIdx.x & 63;
    const int r = pair >> 5, c = pair & 31;
    const float2 av = ((const float2*)(rela + (size_t)r * EMB))[lane];
    const float2 bv = ((const float2*)(rela + (size_t)c * EMB))[lane];
    float dot = av.x * bv.x + av.y * bv.y;
    float na  = av.x * av.x + av.y * av.y;
    float nb  = bv.x * bv.x + bv.y * bv.y;
    #pragma unroll
    for (int off = 32; off > 0; off >>= 1) {
        dot += __shfl_xor(dot, off);
        na  += __shfl_xor(na,  off);
        nb  += __shfl_xor(nb,  off);
    }
    if (lane == 0)
        costab[pair] = fabsf(dot / (sqrtf(na) * sqrtf(nb) + 1e-8f));
}

// ---------------- Kernel A: gather, one (b,j) per wave, PREFETCHED rows -----
// 256-thread blocks (no alloca-demotion risk), all 16 row loads issued
// back-to-back into v[16] BEFORE the softmax, so one latency round-trip per
// wave instead of ~4 serialized groups. ~80 VGPR expected.
__global__ __launch_bounds__(256) void pgra_gather5(
    const int* __restrict__ node, const int* __restrict__ relation,
    const int* __restrict__ adj_node, const int* __restrict__ adj_rela,
    const float* __restrict__ node_table, const float* __restrict__ proj_table,
    const float* __restrict__ costab, float* __restrict__ agg, int npair)
{
    const int p = blockIdx.x * 4 + (threadIdx.x >> 6);
    if (p >= npair) return;
    const int lane = threadIdx.x & 63;
    const int b = p >> 4, j = p & 15;

    const int n0  = node[b];
    const int rel = relation[b];
    const int n1  = adj_node[n0 * KN + j];

    const int4* n2p = (const int4*)(adj_node + (size_t)n1 * KN);
    const int4* r1p = (const int4*)(adj_rela + (size_t)n1 * KN);
    const int4 nn0 = n2p[0], nn1 = n2p[1], nn2 = n2p[2], nn3 = n2p[3];
    const int4 rr0 = r1p[0], rr1 = r1p[1], rr2 = r1p[2], rr3 = r1p[3];

    // ---- issue ALL 16 row loads up front (32 VGPR of results in flight) ----
    float2 v0,v1,v2,v3,v4,v5,v6,v7,v8,v9,v10,v11,v12,v13,v14,v15;
    v0  = ((const float2*)(node_table + (size_t)nn0.x * EMB))[lane];
    v1  = ((const float2*)(node_table + (size_t)nn0.y * EMB))[lane];
    v2  = ((const float2*)(node_table + (size_t)nn0.z * EMB))[lane];
    v3  = ((const float2*)(node_table + (size_t)nn0.w * EMB))[lane];
    v4  = ((const float2*)(node_table + (size_t)nn1.x * EMB))[lane];
    v5  = ((const float2*)(node_table + (size_t)nn1.y * EMB))[lane];
    v6  = ((const float2*)(node_table + (size_t)nn1.z * EMB))[lane];
    v7  = ((const float2*)(node_table + (size_t)nn1.w * EMB))[lane];
    v8  = ((const float2*)(node_table + (size_t)nn2.x * EMB))[lane];
    v9  = ((const float2*)(node_table + (size_t)nn2.y * EMB))[lane];
    v10 = ((const float2*)(node_table + (size_t)nn2.z * EMB))[lane];
    v11 = ((const float2*)(node_table + (size_t)nn2.w * EMB))[lane];
    v12 = ((const float2*)(node_table + (size_t)nn3.x * EMB))[lane];
    v13 = ((const float2*)(node_table + (size_t)nn3.y * EMB))[lane];
    v14 = ((const float2*)(node_table + (size_t)nn3.z * EMB))[lane];
    v15 = ((const float2*)(node_table + (size_t)nn3.w * EMB))[lane];

    // ---- scores + softmax while the row loads are in flight ----
    float sc[KN];
    sc[0]  = costab[rr0.x * NREL + rel]; sc[1]  = costab[rr0.y * NREL + rel];
    sc[2]  = costab[rr0.z * NREL + rel]; sc[3]  = costab[rr0.w * NREL + rel];
    sc[4]  = costab[rr1.x * NREL + rel]; sc[5]  = costab[rr1.y * NREL + rel];
    sc[6]  = costab[rr1.z * NREL + rel]; sc[7]  = costab[rr1.w * NREL + rel];
    sc[8]  = costab[rr2.x * NREL + rel]; sc[9]  = costab[rr2.y * NREL + rel];
    sc[10] = costab[rr2.z * NREL + rel]; sc[11] = costab[rr2.w * NREL + rel];
    sc[12] = costab[rr3.x * NREL + rel]; sc[13] = costab[rr3.y * NREL + rel];
    sc[14] = costab[rr3.z * NREL + rel]; sc[15] = costab[rr3.w * NREL + rel];

    float m = sc[0];
    #pragma unroll
    for (int k = 1; k < KN; ++k) m = fmaxf(m, sc[k]);
    float sum = 0.f;
    #pragma unroll
    for (int k = 0; k < KN; ++k) { sc[k] = __expf(sc[k] - m); sum += sc[k]; }
    const float inv = __fdividef(1.f, sum);

    // ---- weighted sum over prefetched rows ----
    float ax = 0.f, ay = 0.f;
    ax = fmaf(sc[0],  v0.x,  ax); ay = fmaf(sc[0],  v0.y,  ay);
    ax = fmaf(sc[1],  v1.x,  ax); ay = fmaf(sc[1],  v1.y,  ay);
    ax = fmaf(sc[2],  v2.x,  ax); ay = fmaf(sc[2],  v2.y,  ay);
    ax = fmaf(sc[3],  v3.x,  ax); ay = fmaf(sc[3],  v3.y,  ay);
    ax = fmaf(sc[4],  v4.x,  ax); ay = fmaf(sc[4],  v4.y,  ay);
    ax = fmaf(sc[5],  v5.x,  ax); ay = fmaf(sc[5],  v5.y,  ay);
    ax = fmaf(sc[6],  v6.x,  ax); ay = fmaf(sc[6],  v6.y,  ay);
    ax = fmaf(sc[7],  v7.x,  ax); ay = fmaf(sc[7],  v7.y,  ay);
    ax = fmaf(sc[8],  v8.x,  ax); ay = fmaf(sc[8],  v8.y,  ay);
    ax = fmaf(sc[9],  v9.x,  ax); ay = fmaf(sc[9],  v9.y,  ay);
    ax = fmaf(sc[10], v10.x, ax); ay = fmaf(sc[10], v10.y, ay);
    ax = fmaf(sc[11], v11.x, ax); ay = fmaf(sc[11], v11.y, ay);
    ax = fmaf(sc[12], v12.x, ax); ay = fmaf(sc[12], v12.y, ay);
    ax = fmaf(sc[13], v13.x, ax); ay = fmaf(sc[13], v13.y, ay);
    ax = fmaf(sc[14], v14.x, ax); ay = fmaf(sc[14], v14.y, ay);
    ax = fmaf(sc[15], v15.x, ax); ay = fmaf(sc[15], v15.y, ay);

    const float2 pj = ((const float2*)(proj_table + (size_t)rel * EMB))[lane];
    float2 o;
    o.x = ax * inv * pj.x;
    o.y = ay * inv * pj.y;
    ((float2*)(agg + (size_t)p * EMB))[lane] = o;
}

// ---------------- Kernel B: tail4 — one wave per b, 2 output cols per lane ---
// (round-7 verified) Lane owns e = {lane, lane+64}.
__global__ __launch_bounds__(256) void pgra_tail4(
    const int* __restrict__ node, const int* __restrict__ relation,
    const int* __restrict__ adj_rela, const float* __restrict__ agg,
    const float* __restrict__ W0, const float* __restrict__ b0,
    const float* __restrict__ W1, const float* __restrict__ b1,
    const float* __restrict__ costab, float* __restrict__ out)
{
    const int blk  = blockIdx.x;
    const int tid  = threadIdx.x;
    const int wave = tid >> 6;
    const int lane = tid & 63;
    const int b    = blk * 4 + wave;

    __shared__ float s_agg[4][KN][EMB];
    __shared__ float s_fin[4][EMB];

    {
        const float4* ap = (const float4*)(agg + (size_t)blk * 4 * KN * EMB);
        float4* sp = (float4*)&s_agg[0][0][0];
        #pragma unroll
        for (int q = 0; q < 8; ++q) sp[tid + 256 * q] = ap[tid + 256 * q];
    }
    __syncthreads();

    const int n0  = node[b];
    const int rel = relation[b];

    float acc0[KN], acc1[KN];
    const float bias0 = b0[lane];
    const float bias1 = b0[lane + 64];
    #pragma unroll
    for (int k = 0; k < KN; ++k) { acc0[k] = bias0; acc1[k] = bias1; }

    for (int ee4 = 0; ee4 < EMB / 4; ++ee4) {
        const int row = 4 * ee4;
        float w0a[4], w0b[4];
        #pragma unroll
        for (int r = 0; r < 4; ++r) {
            w0a[r] = W0[(row + r) * EMB + lane];
            w0b[r] = W0[(row + r) * EMB + lane + 64];
        }
        #pragma unroll
        for (int k = 0; k < KN; ++k) {
            const float4 a = *(const float4*)&s_agg[wave][k][row];
            acc0[k] = fmaf(a.x, w0a[0], fmaf(a.y, w0a[1], fmaf(a.z, w0a[2], fmaf(a.w, w0a[3], acc0[k]))));
            acc1[k] = fmaf(a.x, w0b[0], fmaf(a.y, w0b[1], fmaf(a.z, w0b[2], fmaf(a.w, w0b[3], acc1[k]))));
        }
    }

    float sc0[KN];
    float m = -1e30f;
    {
        const int4* r0p = (const int4*)(adj_rela + (size_t)n0 * KN);
        #pragma unroll
        for (int q = 0; q < 4; ++q) {
            const int4 rr = r0p[q];
            sc0[4*q+0] = costab[rr.x * NREL + rel];
            sc0[4*q+1] = costab[rr.y * NREL + rel];
            sc0[4*q+2] = costab[rr.z * NREL + rel];
            sc0[4*q+3] = costab[rr.w * NREL + rel];
        }
    }
    #pragma unroll
    for (int k = 0; k < KN; ++k) m = fmaxf(m, sc0[k]);
    float sum = 0.f;
    #pragma unroll
    for (int k = 0; k < KN; ++k) { sc0[k] = __expf(sc0[k] - m); sum += sc0[k]; }
    const float inv = __fdividef(1.f, sum);
    float fin0 = 0.f, fin1 = 0.f;
    #pragma unroll
    for (int k = 0; k < KN; ++k) {
        const float w = sc0[k] * inv;
        fin0 = fmaf(w, fast_tanh(acc0[k]), fin0);
        fin1 = fmaf(w, fast_tanh(acc1[k]), fin1);
    }
    s_fin[wave][lane]      = fin0;
    s_fin[wave][lane + 64] = fin1;
    __syncthreads();

    float o0 = b1[lane], o1 = b1[lane + 64];
    for (int ee4 = 0; ee4 < EMB / 4; ++ee4) {
        const int row = 4 * ee4;
        const float4 f = *(const float4*)&s_fin[wave][row];
        float w1a[4], w1b[4];
        #pragma unroll
        for (int r = 0; r < 4; ++r) {
            w1a[r] = W1[(row + r) * EMB + lane];
            w1b[r] = W1[(row + r) * EMB + lane + 64];
        }
        o0 = fmaf(f.x, w1a[0], fmaf(f.y, w1a[1], fmaf(f.z, w1a[2], fmaf(f.w, w1a[3], o0))));
        o1 = fmaf(f.x, w1b[0], fmaf(f.y, w1b[1], fmaf(f.z, w1b[2], fmaf(f.w, w1b[3], o1))));
    }
    out[(size_t)b * EMB + lane]      = fast_tanh(o0);
    out[(size_t)b * EMB + lane + 64] = fast_tanh(o1);
}

// ---------------- Fallback fused kernel (round-3/4 verified correct) --------
__global__ __launch_bounds__(1024) void pgra_fused(
    const int* __restrict__ node, const int* __restrict__ relation,
    const int* __restrict__ adj_node, const int* __restrict__ adj_rela,
    const float* __restrict__ node_table, const float* __restrict__ proj_table,
    const float* __restrict__ W0, const float* __restrict__ b0,
    const float* __restrict__ W1, const float* __restrict__ b1,
    const float* __restrict__ costab, float* __restrict__ out)
{
    const int b    = blockIdx.x;
    const int tid  = threadIdx.x;
    const int wave = tid >> 6;
    const int lane = tid & 63;

    __shared__ float s_agg[KN][EMB];
    __shared__ float s_part[2][EMB];
    __shared__ float s_fin[EMB];

    const int n0  = node[b];
    const int rel = relation[b];

    {
        const int j  = wave;
        const int n1 = adj_node[n0 * KN + j];
        const int4* n2p = (const int4*)(adj_node + (size_t)n1 * KN);
        const int4* r1p = (const int4*)(adj_rela + (size_t)n1 * KN);
        int   n2[KN];
        float sc[KN];
        #pragma unroll
        for (int q = 0; q < 4; ++q) {
            const int4 nn = n2p[q];
            const int4 rr = r1p[q];
            n2[4*q+0] = nn.x; n2[4*q+1] = nn.y; n2[4*q+2] = nn.z; n2[4*q+3] = nn.w;
            sc[4*q+0] = costab[rr.x * NREL + rel];
            sc[4*q+1] = costab[rr.y * NREL + rel];
            sc[4*q+2] = costab[rr.z * NREL + rel];
            sc[4*q+3] = costab[rr.w * NREL + rel];
        }
        float m = sc[0];
        #pragma unroll
        for (int k = 1; k < KN; ++k) m = fmaxf(m, sc[k]);
        float sum = 0.f;
        #pragma unroll
        for (int k = 0; k < KN; ++k) { sc[k] = __expf(sc[k] - m); sum += sc[k]; }
        const float inv = 1.f / sum;
        float ax = 0.f, ay = 0.f;
        #pragma unroll
        for (int k = 0; k < KN; ++k) {
            const float2 v = ((const float2*)(node_table + (size_t)n2[k] * EMB))[lane];
            ax = fmaf(sc[k], v.x, ax);
            ay = fmaf(sc[k], v.y, ay);
        }
        const float2 pj = ((const float2*)(proj_table + (size_t)rel * EMB))[lane];
        s_agg[j][2*lane]   = ax * inv * pj.x;
        s_agg[j][2*lane+1] = ay * inv * pj.y;
    }
    __syncthreads();

    if (tid < 256) {
        const int e  = tid & 127;
        const int g  = tid >> 7;
        const int jg = g * 8;
        float acc[8];
        const float bias = b0[e];
        #pragma unroll
        for (int q = 0; q < 8; ++q) acc[q] = bias;
        for (int ee4 = 0; ee4 < EMB / 4; ++ee4) {
            const float w0v = W0[(4 * ee4 + 0) * EMB + e];
            const float w1v = W0[(4 * ee4 + 1) * EMB + e];
            const float w2v = W0[(4 * ee4 + 2) * EMB + e];
            const float w3v = W0[(4 * ee4 + 3) * EMB + e];
            #pragma unroll
            for (int q = 0; q < 8; ++q) {
                const float4 a = *(const float4*)&s_agg[jg + q][4 * ee4];
                acc[q] = fmaf(a.x, w0v, fmaf(a.y, w1v, fmaf(a.z, w2v, fmaf(a.w, w3v, acc[q]))));
            }
        }
        float sc0[KN];
        float m = -1e30f;
        #pragma unroll
        for (int k = 0; k < KN; ++k) {
            sc0[k] = costab[adj_rela[n0 * KN + k] * NREL + rel];
            m = fmaxf(m, sc0[k]);
        }
        float sum = 0.f;
        #pragma unroll
        for (int k = 0; k < KN; ++k) { sc0[k] = __expf(sc0[k] - m); sum += sc0[k]; }
        const float inv = 1.f / sum;
        float part = 0.f;
        #pragma unroll
        for (int q = 0; q < 8; ++q)
            part = fmaf(sc0[jg + q] * inv, fast_tanh(acc[q]), part);
        s_part[g][e] = part;
    }
    __syncthreads();

    if (tid < EMB) s_fin[tid] = s_part[0][tid] + s_part[1][tid];
    __syncthreads();

    if (tid < EMB) {
        float acc = b1[tid];
        for (int ee = 0; ee < EMB; ++ee) acc = fmaf(s_fin[ee], W1[ee * EMB + tid], acc);
        out[(size_t)b * EMB + tid] = fast_tanh(acc);
    }
}

extern "C" void kernel_launch(void* const* d_in, const int* in_sizes, int n_in,
                              void* d_out, int out_size, void* d_ws, size_t ws_size,
                              hipStream_t stream) {
    const int*   node       = (const int*)d_in[0];
    const int*   relation   = (const int*)d_in[1];
    const int*   adj_node   = (const int*)d_in[2];
    const int*   adj_rela   = (const int*)d_in[3];
    const float* node_table = (const float*)d_in[4];
    const float* rela_table = (const float*)d_in[5];
    const float* proj_table = (const float*)d_in[6];
    const float* W0         = (const float*)d_in[7];
    const float* b0         = (const float*)d_in[8];
    const float* W1         = (const float*)d_in[9];
    const float* b1         = (const float*)d_in[10];
    float* outp = (float*)d_out;
    const int B = in_sizes[0];

    float* costab = (float*)d_ws;                    // 1024 floats = 4 KB
    float* agg    = (float*)d_ws + 1024;             // B*16*128 floats
    const size_t need = (size_t)(1024 + (size_t)B * KN * EMB) * sizeof(float);

    hipLaunchKernelGGL(pgra_costab_k, dim3(NREL * NREL / 4), dim3(256), 0, stream,
                       rela_table, costab);

    if (ws_size >= need && (B % 4) == 0) {
        const int npair = B * KN;      // 32768 waves, one (b,j) each
        hipLaunchKernelGGL(pgra_gather5, dim3((npair + 3) / 4), dim3(256), 0, stream,
                           node, relation, adj_node, adj_rela,
                           node_table, proj_table, costab, agg, npair);
        hipLaunchKernelGGL(pgra_tail4, dim3(B / 4), dim3(256), 0, stream,
                           node, relation, adj_rela, agg,
                           W0, b0, W1, b1, costab, outp);
    } else {
        hipLaunchKernelGGL(pgra_fused, dim3(B), dim3(1024), 0, stream,
                           node, relation, adj_node, adj_rela,
                           node_table, proj_table, W0, b0, W1, b1, costab, outp);
    }
}

// Round 9
// 79.029 us; speedup vs baseline: 1.0313x; 1.0313x over previous
//
#include <hip/hip_runtime.h>

#define EMB 128
#define KN 16
#define NREL 32

__device__ __forceinline__ float fast_tanh(float x) {
    // exact identity tanh(x) = 1 - 2/(e^{2x}+1); v_exp-based, ~1e-6 abs err.
    const float z = __expf(2.0f * x);
    return 1.0f - __fdividef(2.0f, z + 1.0f);
}

// ---------------- costab: |cos(rela[r], rela[c])| for all 32x32 pairs -------
__global__ __launch_bounds__(256) void pgra_costab_k(const float* __restrict__ rela,
                                                     float* __restrict__ costab) {
    const int pair = blockIdx.x * 4 + (threadIdx.x >> 6);
    const int lane = threadIdx.x & 63;
    const int r = pair >> 5, c = pair & 31;
    const float2 av = ((const float2*)(rela + (size_t)r * EMB))[lane];
    const float2 bv = ((const float2*)(rela + (size_t)c * EMB))[lane];
    float dot = av.x * bv.x + av.y * bv.y;
    float na  = av.x * av.x + av.y * av.y;
    float nb  = bv.x * bv.x + bv.y * bv.y;
    #pragma unroll
    for (int off = 32; off > 0; off >>= 1) {
        dot += __shfl_xor(dot, off);
        na  += __shfl_xor(na,  off);
        nb  += __shfl_xor(nb,  off);
    }
    if (lane == 0)
        costab[pair] = fabsf(dot / (sqrtf(na) * sqrtf(nb) + 1e-8f));
}

// ---------------- Kernel A: gather, prefetched rows PINNED by sched_barrier --
// r8 lesson: source-order prefetch gets re-sunk by the machine scheduler
// (VGPR stayed 40). sched_barrier(0) is a hard scheduling fence: the 16 row
// loads issued above it CANNOT sink into the consumption loop below.
__global__ __launch_bounds__(256) void pgra_gather6(
    const int* __restrict__ node, const int* __restrict__ relation,
    const int* __restrict__ adj_node, const int* __restrict__ adj_rela,
    const float* __restrict__ node_table, const float* __restrict__ proj_table,
    const float* __restrict__ costab, float* __restrict__ agg, int npair)
{
    const int p = blockIdx.x * 4 + (threadIdx.x >> 6);
    if (p >= npair) return;
    const int lane = threadIdx.x & 63;
    const int b = p >> 4, j = p & 15;

    const int n0  = node[b];
    const int rel = relation[b];
    const int n1  = adj_node[n0 * KN + j];

    const int4* n2p = (const int4*)(adj_node + (size_t)n1 * KN);
    const int4* r1p = (const int4*)(adj_rela + (size_t)n1 * KN);
    const int4 nn0 = n2p[0], nn1 = n2p[1], nn2 = n2p[2], nn3 = n2p[3];
    const int4 rr0 = r1p[0], rr1 = r1p[1], rr2 = r1p[2], rr3 = r1p[3];

    // ---- issue ALL 16 row loads; sched_barrier pins them here ----
    float2 v0,v1,v2,v3,v4,v5,v6,v7,v8,v9,v10,v11,v12,v13,v14,v15;
    v0  = ((const float2*)(node_table + (size_t)nn0.x * EMB))[lane];
    v1  = ((const float2*)(node_table + (size_t)nn0.y * EMB))[lane];
    v2  = ((const float2*)(node_table + (size_t)nn0.z * EMB))[lane];
    v3  = ((const float2*)(node_table + (size_t)nn0.w * EMB))[lane];
    v4  = ((const float2*)(node_table + (size_t)nn1.x * EMB))[lane];
    v5  = ((const float2*)(node_table + (size_t)nn1.y * EMB))[lane];
    v6  = ((const float2*)(node_table + (size_t)nn1.z * EMB))[lane];
    v7  = ((const float2*)(node_table + (size_t)nn1.w * EMB))[lane];
    v8  = ((const float2*)(node_table + (size_t)nn2.x * EMB))[lane];
    v9  = ((const float2*)(node_table + (size_t)nn2.y * EMB))[lane];
    v10 = ((const float2*)(node_table + (size_t)nn2.z * EMB))[lane];
    v11 = ((const float2*)(node_table + (size_t)nn2.w * EMB))[lane];
    v12 = ((const float2*)(node_table + (size_t)nn3.x * EMB))[lane];
    v13 = ((const float2*)(node_table + (size_t)nn3.y * EMB))[lane];
    v14 = ((const float2*)(node_table + (size_t)nn3.z * EMB))[lane];
    v15 = ((const float2*)(node_table + (size_t)nn3.w * EMB))[lane];
    __builtin_amdgcn_sched_barrier(0);   // loads may NOT sink below this line

    // ---- scores + softmax while the row loads are in flight ----
    float sc[KN];
    sc[0]  = costab[rr0.x * NREL + rel]; sc[1]  = costab[rr0.y * NREL + rel];
    sc[2]  = costab[rr0.z * NREL + rel]; sc[3]  = costab[rr0.w * NREL + rel];
    sc[4]  = costab[rr1.x * NREL + rel]; sc[5]  = costab[rr1.y * NREL + rel];
    sc[6]  = costab[rr1.z * NREL + rel]; sc[7]  = costab[rr1.w * NREL + rel];
    sc[8]  = costab[rr2.x * NREL + rel]; sc[9]  = costab[rr2.y * NREL + rel];
    sc[10] = costab[rr2.z * NREL + rel]; sc[11] = costab[rr2.w * NREL + rel];
    sc[12] = costab[rr3.x * NREL + rel]; sc[13] = costab[rr3.y * NREL + rel];
    sc[14] = costab[rr3.z * NREL + rel]; sc[15] = costab[rr3.w * NREL + rel];

    float m = sc[0];
    #pragma unroll
    for (int k = 1; k < KN; ++k) m = fmaxf(m, sc[k]);
    float sum = 0.f;
    #pragma unroll
    for (int k = 0; k < KN; ++k) { sc[k] = __expf(sc[k] - m); sum += sc[k]; }
    const float inv = __fdividef(1.f, sum);

    // ---- weighted sum over prefetched rows ----
    float ax = 0.f, ay = 0.f;
    ax = fmaf(sc[0],  v0.x,  ax); ay = fmaf(sc[0],  v0.y,  ay);
    ax = fmaf(sc[1],  v1.x,  ax); ay = fmaf(sc[1],  v1.y,  ay);
    ax = fmaf(sc[2],  v2.x,  ax); ay = fmaf(sc[2],  v2.y,  ay);
    ax = fmaf(sc[3],  v3.x,  ax); ay = fmaf(sc[3],  v3.y,  ay);
    ax = fmaf(sc[4],  v4.x,  ax); ay = fmaf(sc[4],  v4.y,  ay);
    ax = fmaf(sc[5],  v5.x,  ax); ay = fmaf(sc[5],  v5.y,  ay);
    ax = fmaf(sc[6],  v6.x,  ax); ay = fmaf(sc[6],  v6.y,  ay);
    ax = fmaf(sc[7],  v7.x,  ax); ay = fmaf(sc[7],  v7.y,  ay);
    ax = fmaf(sc[8],  v8.x,  ax); ay = fmaf(sc[8],  v8.y,  ay);
    ax = fmaf(sc[9],  v9.x,  ax); ay = fmaf(sc[9],  v9.y,  ay);
    ax = fmaf(sc[10], v10.x, ax); ay = fmaf(sc[10], v10.y, ay);
    ax = fmaf(sc[11], v11.x, ax); ay = fmaf(sc[11], v11.y, ay);
    ax = fmaf(sc[12], v12.x, ax); ay = fmaf(sc[12], v12.y, ay);
    ax = fmaf(sc[13], v13.x, ax); ay = fmaf(sc[13], v13.y, ay);
    ax = fmaf(sc[14], v14.x, ax); ay = fmaf(sc[14], v14.y, ay);
    ax = fmaf(sc[15], v15.x, ax); ay = fmaf(sc[15], v15.y, ay);

    const float2 pj = ((const float2*)(proj_table + (size_t)rel * EMB))[lane];
    float2 o;
    o.x = ax * inv * pj.x;
    o.y = ay * inv * pj.y;
    ((float2*)(agg + (size_t)p * EMB))[lane] = o;
}

// ---------------- Kernel B: tail8 — 8 b's per 512-thread block --------------
// One wave per b, lane owns output cols {lane, lane+64}. W0/W1 unique-read
// once per block (L1 dedups across the 8 lockstep waves): 128 KB per block,
// 256 blocks -> 32 MB L2 traffic (half of tail4). LDS exactly 64 KB; only ONE
// barrier (after staging) — each wave reads/writes only its own tile after.
__global__ __launch_bounds__(512) void pgra_tail8(
    const int* __restrict__ node, const int* __restrict__ relation,
    const int* __restrict__ adj_rela, const float* __restrict__ agg,
    const float* __restrict__ W0, const float* __restrict__ b0,
    const float* __restrict__ W1, const float* __restrict__ b1,
    const float* __restrict__ costab, float* __restrict__ out)
{
    const int blk  = blockIdx.x;          // B/8 blocks
    const int tid  = threadIdx.x;         // 0..511
    const int wave = tid >> 6;            // 0..7 -> which b
    const int lane = tid & 63;
    const int b    = blk * 8 + wave;

    __shared__ float s_agg[8][KN][EMB];   // 64 KB exactly

    // stage 8 agg tiles (16384 floats = 4096 float4), fully coalesced
    {
        const float4* ap = (const float4*)(agg + (size_t)blk * 8 * KN * EMB);
        float4* sp = (float4*)&s_agg[0][0][0];
        #pragma unroll
        for (int q = 0; q < 8; ++q) sp[tid + 512 * q] = ap[tid + 512 * q];
    }
    __syncthreads();                      // the only barrier

    const int n0  = node[b];              // wave-uniform
    const int rel = relation[b];

    float acc0[KN], acc1[KN];
    const float bias0 = b0[lane];
    const float bias1 = b0[lane + 64];
    #pragma unroll
    for (int k = 0; k < KN; ++k) { acc0[k] = bias0; acc1[k] = bias1; }

    for (int ee4 = 0; ee4 < EMB / 4; ++ee4) {
        const int row = 4 * ee4;
        float w0a[4], w0b[4];
        #pragma unroll
        for (int r = 0; r < 4; ++r) {
            w0a[r] = W0[(row + r) * EMB + lane];
            w0b[r] = W0[(row + r) * EMB + lane + 64];
        }
        #pragma unroll
        for (int k = 0; k < KN; ++k) {
            const float4 a = *(const float4*)&s_agg[wave][k][row];   // broadcast
            acc0[k] = fmaf(a.x, w0a[0], fmaf(a.y, w0a[1], fmaf(a.z, w0a[2], fmaf(a.w, w0a[3], acc0[k]))));
            acc1[k] = fmaf(a.x, w0b[0], fmaf(a.y, w0b[1], fmaf(a.z, w0b[2], fmaf(a.w, w0b[3], acc1[k]))));
        }
    }

    // hop-2 attention weights (from r0), folded in-register with fast_tanh
    float sc0[KN];
    float m = -1e30f;
    {
        const int4* r0p = (const int4*)(adj_rela + (size_t)n0 * KN);
        #pragma unroll
        for (int q = 0; q < 4; ++q) {
            const int4 rr = r0p[q];
            sc0[4*q+0] = costab[rr.x * NREL + rel];
            sc0[4*q+1] = costab[rr.y * NREL + rel];
            sc0[4*q+2] = costab[rr.z * NREL + rel];
            sc0[4*q+3] = costab[rr.w * NREL + rel];
        }
    }
    #pragma unroll
    for (int k = 0; k < KN; ++k) m = fmaxf(m, sc0[k]);
    float sum = 0.f;
    #pragma unroll
    for (int k = 0; k < KN; ++k) { sc0[k] = __expf(sc0[k] - m); sum += sc0[k]; }
    const float inv = __fdividef(1.f, sum);
    float fin0 = 0.f, fin1 = 0.f;
    #pragma unroll
    for (int k = 0; k < KN; ++k) {
        const float w = sc0[k] * inv;
        fin0 = fmaf(w, fast_tanh(acc0[k]), fin0);
        fin1 = fmaf(w, fast_tanh(acc1[k]), fin1);
    }
    // park fin in this wave's OWN tile (its matvec reads are complete; no
    // other wave touches this region -> no barrier needed)
    s_agg[wave][0][lane]      = fin0;
    s_agg[wave][0][lane + 64] = fin1;
    __builtin_amdgcn_wave_barrier();      // order within wave (no-op cost)

    float o0 = b1[lane], o1 = b1[lane + 64];
    for (int ee4 = 0; ee4 < EMB / 4; ++ee4) {
        const int row = 4 * ee4;
        const float4 f = *(const float4*)&s_agg[wave][0][row];       // broadcast
        float w1a[4], w1b[4];
        #pragma unroll
        for (int r = 0; r < 4; ++r) {
            w1a[r] = W1[(row + r) * EMB + lane];
            w1b[r] = W1[(row + r) * EMB + lane + 64];
        }
        o0 = fmaf(f.x, w1a[0], fmaf(f.y, w1a[1], fmaf(f.z, w1a[2], fmaf(f.w, w1a[3], o0))));
        o1 = fmaf(f.x, w1b[0], fmaf(f.y, w1b[1], fmaf(f.z, w1b[2], fmaf(f.w, w1b[3], o1))));
    }
    out[(size_t)b * EMB + lane]      = fast_tanh(o0);
    out[(size_t)b * EMB + lane + 64] = fast_tanh(o1);
}

// ---------------- Fallback fused kernel (round-3/4 verified correct) --------
__global__ __launch_bounds__(1024) void pgra_fused(
    const int* __restrict__ node, const int* __restrict__ relation,
    const int* __restrict__ adj_node, const int* __restrict__ adj_rela,
    const float* __restrict__ node_table, const float* __restrict__ proj_table,
    const float* __restrict__ W0, const float* __restrict__ b0,
    const float* __restrict__ W1, const float* __restrict__ b1,
    const float* __restrict__ costab, float* __restrict__ out)
{
    const int b    = blockIdx.x;
    const int tid  = threadIdx.x;
    const int wave = tid >> 6;
    const int lane = tid & 63;

    __shared__ float s_agg[KN][EMB];
    __shared__ float s_part[2][EMB];
    __shared__ float s_fin[EMB];

    const int n0  = node[b];
    const int rel = relation[b];

    {
        const int j  = wave;
        const int n1 = adj_node[n0 * KN + j];
        const int4* n2p = (const int4*)(adj_node + (size_t)n1 * KN);
        const int4* r1p = (const int4*)(adj_rela + (size_t)n1 * KN);
        int   n2[KN];
        float sc[KN];
        #pragma unroll
        for (int q = 0; q < 4; ++q) {
            const int4 nn = n2p[q];
            const int4 rr = r1p[q];
            n2[4*q+0] = nn.x; n2[4*q+1] = nn.y; n2[4*q+2] = nn.z; n2[4*q+3] = nn.w;
            sc[4*q+0] = costab[rr.x * NREL + rel];
            sc[4*q+1] = costab[rr.y * NREL + rel];
            sc[4*q+2] = costab[rr.z * NREL + rel];
            sc[4*q+3] = costab[rr.w * NREL + rel];
        }
        float m = sc[0];
        #pragma unroll
        for (int k = 1; k < KN; ++k) m = fmaxf(m, sc[k]);
        float sum = 0.f;
        #pragma unroll
        for (int k = 0; k < KN; ++k) { sc[k] = __expf(sc[k] - m); sum += sc[k]; }
        const float inv = 1.f / sum;
        float ax = 0.f, ay = 0.f;
        #pragma unroll
        for (int k = 0; k < KN; ++k) {
            const float2 v = ((const float2*)(node_table + (size_t)n2[k] * EMB))[lane];
            ax = fmaf(sc[k], v.x, ax);
            ay = fmaf(sc[k], v.y, ay);
        }
        const float2 pj = ((const float2*)(proj_table + (size_t)rel * EMB))[lane];
        s_agg[j][2*lane]   = ax * inv * pj.x;
        s_agg[j][2*lane+1] = ay * inv * pj.y;
    }
    __syncthreads();

    if (tid < 256) {
        const int e  = tid & 127;
        const int g  = tid >> 7;
        const int jg = g * 8;
        float acc[8];
        const float bias = b0[e];
        #pragma unroll
        for (int q = 0; q < 8; ++q) acc[q] = bias;
        for (int ee4 = 0; ee4 < EMB / 4; ++ee4) {
            const float w0v = W0[(4 * ee4 + 0) * EMB + e];
            const float w1v = W0[(4 * ee4 + 1) * EMB + e];
            const float w2v = W0[(4 * ee4 + 2) * EMB + e];
            const float w3v = W0[(4 * ee4 + 3) * EMB + e];
            #pragma unroll
            for (int q = 0; q < 8; ++q) {
                const float4 a = *(const float4*)&s_agg[jg + q][4 * ee4];
                acc[q] = fmaf(a.x, w0v, fmaf(a.y, w1v, fmaf(a.z, w2v, fmaf(a.w, w3v, acc[q]))));
            }
        }
        float sc0[KN];
        float m = -1e30f;
        #pragma unroll
        for (int k = 0; k < KN; ++k) {
            sc0[k] = costab[adj_rela[n0 * KN + k] * NREL + rel];
            m = fmaxf(m, sc0[k]);
        }
        float sum = 0.f;
        #pragma unroll
        for (int k = 0; k < KN; ++k) { sc0[k] = __expf(sc0[k] - m); sum += sc0[k]; }
        const float inv = 1.f / sum;
        float part = 0.f;
        #pragma unroll
        for (int q = 0; q < 8; ++q)
            part = fmaf(sc0[jg + q] * inv, fast_tanh(acc[q]), part);
        s_part[g][e] = part;
    }
    __syncthreads();

    if (tid < EMB) s_fin[tid] = s_part[0][tid] + s_part[1][tid];
    __syncthreads();

    if (tid < EMB) {
        float acc = b1[tid];
        for (int ee = 0; ee < EMB; ++ee) acc = fmaf(s_fin[ee], W1[ee * EMB + tid], acc);
        out[(size_t)b * EMB + tid] = fast_tanh(acc);
    }
}

extern "C" void kernel_launch(void* const* d_in, const int* in_sizes, int n_in,
                              void* d_out, int out_size, void* d_ws, size_t ws_size,
                              hipStream_t stream) {
    const int*   node       = (const int*)d_in[0];
    const int*   relation   = (const int*)d_in[1];
    const int*   adj_node   = (const int*)d_in[2];
    const int*   adj_rela   = (const int*)d_in[3];
    const float* node_table = (const float*)d_in[4];
    const float* rela_table = (const float*)d_in[5];
    const float* proj_table = (const float*)d_in[6];
    const float* W0         = (const float*)d_in[7];
    const float* b0         = (const float*)d_in[8];
    const float* W1         = (const float*)d_in[9];
    const float* b1         = (const float*)d_in[10];
    float* outp = (float*)d_out;
    const int B = in_sizes[0];

    float* costab = (float*)d_ws;                    // 1024 floats = 4 KB
    float* agg    = (float*)d_ws + 1024;             // B*16*128 floats
    const size_t need = (size_t)(1024 + (size_t)B * KN * EMB) * sizeof(float);

    hipLaunchKernelGGL(pgra_costab_k, dim3(NREL * NREL / 4), dim3(256), 0, stream,
                       rela_table, costab);

    if (ws_size >= need && (B % 8) == 0) {
        const int npair = B * KN;      // 32768 waves, one (b,j) each
        hipLaunchKernelGGL(pgra_gather6, dim3((npair + 3) / 4), dim3(256), 0, stream,
                           node, relation, adj_node, adj_rela,
                           node_table, proj_table, costab, agg, npair);
        hipLaunchKernelGGL(pgra_tail8, dim3(B / 8), dim3(512), 0, stream,
                           node, relation, adj_rela, agg,
                           W0, b0, W1, b1, costab, outp);
    } else {
        hipLaunchKernelGGL(pgra_fused, dim3(B), dim3(1024), 0, stream,
                           node, relation, adj_node, adj_rela,
                           node_table, proj_table, W0, b0, W1, b1, costab, outp);
    }
}